// Round 1
// baseline (213.414 us; speedup 1.0000x reference)
//
#include <hip/hip_runtime.h>
#include <hip/hip_bf16.h>
#include <cstdint>
#include <cstddef>

#define M_DIM 4096
#define N_DIM 4096
#define K_DIM 4096

using f32x4  = __attribute__((ext_vector_type(4))) float;
using bf16x8 = __attribute__((ext_vector_type(8))) short;   // 8 bf16 in 4 VGPRs
using float4v = __attribute__((ext_vector_type(4))) float;

__device__ __forceinline__ ushort f32_to_bf16_rne(float f) {
    uint32_t u = __builtin_bit_cast(uint32_t, f);
    uint32_t rnd = 0x7FFFu + ((u >> 16) & 1u);
    return (ushort)((u + rnd) >> 16);
}

__device__ __forceinline__ void gload_lds16(const void* g, void* l) {
    __builtin_amdgcn_global_load_lds(
        (const __attribute__((address_space(1))) uint32_t*)g,
        (__attribute__((address_space(3))) uint32_t*)l, 16, 0, 0);
}

// ---------------- pass 1a: x (f32) -> bf16, row-major M x K ----------------
__global__ __launch_bounds__(256) void cvt_x_kernel(const float* __restrict__ x,
                                                    ushort* __restrict__ xq,
                                                    int n8) {
    int idx = blockIdx.x * blockDim.x + threadIdx.x;
    int stride = gridDim.x * blockDim.x;
    for (int i = idx; i < n8; i += stride) {
        const float4v* p = (const float4v*)(x + (size_t)i * 8);
        float4v v0 = p[0];
        float4v v1 = p[1];
        bf16x8 o;
        o[0] = (short)f32_to_bf16_rne(v0[0]);
        o[1] = (short)f32_to_bf16_rne(v0[1]);
        o[2] = (short)f32_to_bf16_rne(v0[2]);
        o[3] = (short)f32_to_bf16_rne(v0[3]);
        o[4] = (short)f32_to_bf16_rne(v1[0]);
        o[5] = (short)f32_to_bf16_rne(v1[1]);
        o[6] = (short)f32_to_bf16_rne(v1[2]);
        o[7] = (short)f32_to_bf16_rne(v1[3]);
        *(bf16x8*)(xq + (size_t)i * 8) = o;
    }
}

// ------- pass 1b: W (K x N, f32) -> sign -> bf16, TRANSPOSED to N x K -------
__global__ __launch_bounds__(256) void sign_wt_kernel(const float* __restrict__ W,
                                                      ushort* __restrict__ WqT) {
    __shared__ ushort tile[32][34];   // +2 pad: 68B row stride, odd bank step
    int j0 = blockIdx.x * 32;         // N coordinate of W
    int k0 = blockIdx.y * 32;         // K coordinate of W
    int tx = threadIdx.x;             // 0..31
    int ty = threadIdx.y;             // 0..7
#pragma unroll
    for (int i = 0; i < 4; ++i) {
        int kk = ty + i * 8;
        float w = W[(size_t)(k0 + kk) * N_DIM + (j0 + tx)];
        tile[kk][tx] = (w > 0.f) ? (ushort)0x3F80
                     : (w < 0.f) ? (ushort)0xBF80 : (ushort)0x0000;
    }
    __syncthreads();
#pragma unroll
    for (int i = 0; i < 4; ++i) {
        int jj = ty + i * 8;
        WqT[(size_t)(j0 + jj) * K_DIM + (k0 + tx)] = tile[tx][jj];
    }
}

// ---------------- pass 2: C = Xq @ WqT^T + b  (bf16 MFMA GEMM) ----------------
// m97 structure: 128x128 tile, BK=32, 4 waves (2x2), acc[4][4], 16x16x32 bf16,
// global_load_lds width=16 staging, 2 barriers per K-step.
__global__ __launch_bounds__(256) void gemm_bin_kernel(const ushort* __restrict__ A,  // M x K bf16
                                                       const ushort* __restrict__ B,  // N x K bf16
                                                       const float* __restrict__ bias,
                                                       float* __restrict__ C) {
    __shared__ __align__(16) ushort As[128 * 32];
    __shared__ __align__(16) ushort Bs[128 * 32];

    // XCD-aware bijective swizzle (nwg = 1024, divisible by 8)
    int bid = blockIdx.x;
    int cpx = gridDim.x >> 3;
    int swz = (bid & 7) * cpx + (bid >> 3);
    const int tiles_n = N_DIM / 128;            // 32
    int brow = (swz / tiles_n) * 128;
    int bcol = (swz % tiles_n) * 128;

    int t = threadIdx.x;
    int lane = t & 63;
    int wid  = t >> 6;
    int wr = wid >> 1, wc = wid & 1;            // 2x2 wave grid, 64x64 per wave

    // staging: thread t covers tile elements e = c*2048 + t*8 .. +8 (row = e/32)
    int r0 = t >> 2;                            // 0..63
    int c0 = (t & 3) << 3;                      // 0/8/16/24

    const ushort* Ag0 = A + (size_t)(brow + r0) * K_DIM + c0;
    const ushort* Ag1 = Ag0 + (size_t)64 * K_DIM;
    const ushort* Bg0 = B + (size_t)(bcol + r0) * K_DIM + c0;
    const ushort* Bg1 = Bg0 + (size_t)64 * K_DIM;

    ushort* AsD0 = As + t * 8;                  // byte offset t*16 (linear, per-wave uniform base)
    ushort* AsD1 = As + 2048 + t * 8;
    ushort* BsD0 = Bs + t * 8;
    ushort* BsD1 = Bs + 2048 + t * 8;

    f32x4 acc[4][4];
#pragma unroll
    for (int m = 0; m < 4; ++m)
#pragma unroll
        for (int n = 0; n < 4; ++n)
            acc[m][n] = (f32x4){0.f, 0.f, 0.f, 0.f};

    int klo  = lane >> 4;                       // 0..3
    int lrow = lane & 15;                       // 0..15

    // A frag m: As[(wr*64 + m*16 + lrow)*32 + klo*8]  (8 contiguous bf16, 16B aligned)
    const ushort* ArdBase = As + ((wr * 64 + lrow) * 32 + klo * 8);
    const ushort* BrdBase = Bs + ((wc * 64 + lrow) * 32 + klo * 8);

    for (int kt = 0; kt < K_DIM / 32; ++kt) {
        int ko = kt * 32;
        gload_lds16(Ag0 + ko, AsD0);
        gload_lds16(Ag1 + ko, AsD1);
        gload_lds16(Bg0 + ko, BsD0);
        gload_lds16(Bg1 + ko, BsD1);
        __syncthreads();                        // drains vmcnt(0): tile resident

        bf16x8 a[4], b[4];
#pragma unroll
        for (int m = 0; m < 4; ++m)
            a[m] = *(const bf16x8*)(ArdBase + m * 16 * 32);
#pragma unroll
        for (int n = 0; n < 4; ++n)
            b[n] = *(const bf16x8*)(BrdBase + n * 16 * 32);

#pragma unroll
        for (int m = 0; m < 4; ++m)
#pragma unroll
            for (int n = 0; n < 4; ++n)
                acc[m][n] = __builtin_amdgcn_mfma_f32_16x16x32_bf16(a[m], b[n], acc[m][n], 0, 0, 0);

        __syncthreads();                        // protect LDS before next stage
    }

    // epilogue: D col = lane&15, row = (lane>>4)*4 + reg  (m89-verified layout)
    int crow = brow + wr * 64 + klo * 4;
    int ccol = bcol + wc * 64 + lrow;
#pragma unroll
    for (int n = 0; n < 4; ++n) {
        int col = ccol + n * 16;
        float bv = bias[col];
#pragma unroll
        for (int m = 0; m < 4; ++m) {
            int row = crow + m * 16;
#pragma unroll
            for (int r = 0; r < 4; ++r) {
                C[(size_t)(row + r) * N_DIM + col] = acc[m][n][r] + bv;
            }
        }
    }
}

extern "C" void kernel_launch(void* const* d_in, const int* in_sizes, int n_in,
                              void* d_out, int out_size, void* d_ws, size_t ws_size,
                              hipStream_t stream) {
    const float* x = (const float*)d_in[0];   // (4096, 4096) f32
    const float* W = (const float*)d_in[1];   // (4096, 4096) f32
    const float* b = (const float*)d_in[2];   // (4096,) f32
    float* out = (float*)d_out;               // (4096, 4096) f32

    ushort* xq  = (ushort*)d_ws;                               // 32 MB: X as bf16 (M x K)
    ushort* WqT = (ushort*)d_ws + (size_t)M_DIM * K_DIM;       // 32 MB: sign(W) as bf16, N x K

    cvt_x_kernel<<<2048, 256, 0, stream>>>(x, xq, M_DIM * K_DIM / 8);
    sign_wt_kernel<<<dim3(N_DIM / 32, K_DIM / 32), dim3(32, 8), 0, stream>>>(W, WqT);
    gemm_bin_kernel<<<dim3((M_DIM / 128) * (N_DIM / 128)), dim3(256), 0, stream>>>(xq, WqT, b, out);
}

// Round 2
// 149.153 us; speedup vs baseline: 1.4308x; 1.4308x over previous
//
#include <hip/hip_runtime.h>
#include <hip/hip_bf16.h>
#include <cstdint>
#include <cstddef>

#define M_DIM 4096
#define N_DIM 4096
#define K_DIM 4096
#define NT    (K_DIM / 64)   // 64 K-tiles of BK=64

using f32x4   = __attribute__((ext_vector_type(4))) float;
using bf16x8  = __attribute__((ext_vector_type(8))) short;   // 8 bf16 in 4 VGPRs
using float4v = __attribute__((ext_vector_type(4))) float;

__device__ __forceinline__ ushort f32_to_bf16_rne(float f) {
    uint32_t u = __builtin_bit_cast(uint32_t, f);
    uint32_t rnd = 0x7FFFu + ((u >> 16) & 1u);
    return (ushort)((u + rnd) >> 16);
}

__device__ __forceinline__ void gload_lds16(const void* g, void* l) {
    __builtin_amdgcn_global_load_lds(
        (const __attribute__((address_space(1))) uint32_t*)g,
        (__attribute__((address_space(3))) uint32_t*)l, 16, 0, 0);
}

// ---------------- pass 1a: x (f32) -> bf16, row-major M x K ----------------
__global__ __launch_bounds__(256) void cvt_x_kernel(const float* __restrict__ x,
                                                    ushort* __restrict__ xq,
                                                    int n8) {
    int idx = blockIdx.x * blockDim.x + threadIdx.x;
    int stride = gridDim.x * blockDim.x;
    for (int i = idx; i < n8; i += stride) {
        const float4v* p = (const float4v*)(x + (size_t)i * 8);
        float4v v0 = p[0];
        float4v v1 = p[1];
        bf16x8 o;
        o[0] = (short)f32_to_bf16_rne(v0[0]);
        o[1] = (short)f32_to_bf16_rne(v0[1]);
        o[2] = (short)f32_to_bf16_rne(v0[2]);
        o[3] = (short)f32_to_bf16_rne(v0[3]);
        o[4] = (short)f32_to_bf16_rne(v1[0]);
        o[5] = (short)f32_to_bf16_rne(v1[1]);
        o[6] = (short)f32_to_bf16_rne(v1[2]);
        o[7] = (short)f32_to_bf16_rne(v1[3]);
        *(bf16x8*)(xq + (size_t)i * 8) = o;
    }
}

// ------- pass 1b: W (K x N, f32) -> sign -> bf16, TRANSPOSED to N x K -------
__global__ __launch_bounds__(256) void sign_wt_kernel(const float* __restrict__ W,
                                                      ushort* __restrict__ WqT) {
    __shared__ ushort tile[32][34];
    int j0 = blockIdx.x * 32;
    int k0 = blockIdx.y * 32;
    int tx = threadIdx.x;
    int ty = threadIdx.y;
#pragma unroll
    for (int i = 0; i < 4; ++i) {
        int kk = ty + i * 8;
        float w = W[(size_t)(k0 + kk) * N_DIM + (j0 + tx)];
        tile[kk][tx] = (w > 0.f) ? (ushort)0x3F80
                     : (w < 0.f) ? (ushort)0xBF80 : (ushort)0x0000;
    }
    __syncthreads();
#pragma unroll
    for (int i = 0; i < 4; ++i) {
        int jj = ty + i * 8;
        WqT[(size_t)(j0 + jj) * K_DIM + (k0 + tx)] = tile[tx][jj];
    }
}

// ------------- pass 2: 256x256-tile 8-phase bf16 MFMA GEMM (T1..T5) -------------
// C = Xq(MxK) * WqT(NxK)^T + b. 8 waves (2Mx4N), BK=64, double-buffered 128KiB LDS,
// st-swizzled fragments, counted vmcnt(8), setprio around MFMA clusters.

#define STAGE_A(p, h, kt) do {                                                   \
    const ushort* _g = Abase + (size_t)((h) * 128) * K_DIM + (kt) * 64;          \
    gload_lds16(_g, &lds[(p) * 16384 + (h) * 8192 + ldso]);                      \
    gload_lds16(_g + (size_t)64 * K_DIM,                                         \
                &lds[(p) * 16384 + (h) * 8192 + 4096 + ldso]);                   \
} while (0)

#define STAGE_B(p, h, kt) do {                                                   \
    const ushort* _g = Bbase + (size_t)((h) * 128) * K_DIM + (kt) * 64;          \
    gload_lds16(_g, &lds[32768 + (p) * 16384 + (h) * 8192 + ldso]);              \
    gload_lds16(_g + (size_t)64 * K_DIM,                                         \
                &lds[32768 + (p) * 16384 + (h) * 8192 + 4096 + ldso]);           \
} while (0)

// A frag bytes: p*32768 + wr*16384 + mh*8192 + mq*2048 + lrow*128 + koff(kk)
#define RD_A(p, mh, mq, kk)                                                      \
    (*(const bf16x8*)(ldsc + (p) * 32768 + aB + (mh) * 8192 + (mq) * 2048 +      \
                      ((kk) ? koff1 : koff0)))
// B frag bytes: 65536 + p*32768 + (wc>>1)*16384 + (wc&1)*8192 + nh*4096 + nq*2048 + lrow*128 + koff(kk)
#define RD_B(p, nh, nq, kk)                                                      \
    (*(const bf16x8*)(ldsc + (p) * 32768 + bB + (nh) * 4096 + (nq) * 2048 +      \
                      ((kk) ? koff1 : koff0)))

#define MFMA_QUAD(mh, nh, bArr) do {                                             \
    __builtin_amdgcn_s_setprio(1);                                               \
    _Pragma("unroll")                                                            \
    for (int mq = 0; mq < 4; ++mq)                                               \
        _Pragma("unroll")                                                        \
        for (int nq = 0; nq < 2; ++nq)                                           \
            _Pragma("unroll")                                                    \
            for (int kk = 0; kk < 2; ++kk)                                       \
                acc[(mh) * 4 + mq][(nh) * 2 + nq] =                              \
                    __builtin_amdgcn_mfma_f32_16x16x32_bf16(                     \
                        aF[mq][kk], bArr[nq][kk],                                \
                        acc[(mh) * 4 + mq][(nh) * 2 + nq], 0, 0, 0);             \
    __builtin_amdgcn_s_setprio(0);                                               \
} while (0)

#define TILE(kt, p) do {                                                         \
    /* q0: reads A[mh0] (8) + B[nh0] (4); compute (mh0,nh0) */                   \
    _Pragma("unroll")                                                            \
    for (int mq = 0; mq < 4; ++mq) {                                             \
        aF[mq][0] = RD_A(p, 0, mq, 0); aF[mq][1] = RD_A(p, 0, mq, 1);            \
    }                                                                            \
    _Pragma("unroll")                                                            \
    for (int nq = 0; nq < 2; ++nq) {                                             \
        bL[nq][0] = RD_B(p, 0, nq, 0); bL[nq][1] = RD_B(p, 0, nq, 1);            \
    }                                                                            \
    __builtin_amdgcn_s_barrier();                                                \
    asm volatile("s_waitcnt lgkmcnt(0)");                                        \
    MFMA_QUAD(0, 0, bL);                                                         \
    __builtin_amdgcn_s_barrier();                                                \
    /* q1: reads B[nh1] (4); compute (mh0,nh1) */                                \
    _Pragma("unroll")                                                            \
    for (int nq = 0; nq < 2; ++nq) {                                             \
        bH[nq][0] = RD_B(p, 1, nq, 0); bH[nq][1] = RD_B(p, 1, nq, 1);            \
    }                                                                            \
    __builtin_amdgcn_s_barrier();                                                \
    asm volatile("s_waitcnt lgkmcnt(0)");                                        \
    MFMA_QUAD(0, 1, bH);                                                         \
    __builtin_amdgcn_s_barrier();                                                \
    /* q2: stage B halves of kt+2 (B regions freed at q1-end barrier);           \
           reads A[mh1] (8); compute (mh1,nh1) */                                \
    if ((kt) + 2 < NT) { STAGE_B(p, 0, (kt) + 2); STAGE_B(p, 1, (kt) + 2); }     \
    _Pragma("unroll")                                                            \
    for (int mq = 0; mq < 4; ++mq) {                                             \
        aF[mq][0] = RD_A(p, 1, mq, 0); aF[mq][1] = RD_A(p, 1, mq, 1);            \
    }                                                                            \
    __builtin_amdgcn_s_barrier();                                                \
    asm volatile("s_waitcnt lgkmcnt(0)");                                        \
    MFMA_QUAD(1, 1, bH);                                                         \
    __builtin_amdgcn_s_barrier();                                                \
    /* q3: stage A halves of kt+2 (A regions freed at q2-end barrier);           \
           compute (mh1,nh0); counted vmcnt: tile kt+1 landed, kt+2 in flight */ \
    if ((kt) + 2 < NT) { STAGE_A(p, 0, (kt) + 2); STAGE_A(p, 1, (kt) + 2); }     \
    __builtin_amdgcn_s_barrier();                                                \
    MFMA_QUAD(1, 0, bL);                                                         \
    if ((kt) + 2 < NT) { asm volatile("s_waitcnt vmcnt(8)"); }                   \
    else               { asm volatile("s_waitcnt vmcnt(0)"); }                   \
    __builtin_amdgcn_s_barrier();                                                \
} while (0)

__global__ __launch_bounds__(512, 1) void gemm_bin_kernel(const ushort* __restrict__ A,  // M x K bf16
                                                          const ushort* __restrict__ B,  // N x K bf16
                                                          const float* __restrict__ bias,
                                                          float* __restrict__ C) {
    __shared__ __align__(16) ushort lds[65536];   // 128 KiB: A[2][2][128][64], B[2][2][128][64]

    // T1: XCD-aware bijective swizzle (256 wgs, 256 % 8 == 0)
    int bid  = blockIdx.x;
    int swz  = (bid & 7) * 32 + (bid >> 3);
    int brow = (swz >> 4) << 8;
    int bcol = (swz & 15) << 8;

    int t    = threadIdx.x;
    int lane = t & 63;
    int wid  = t >> 6;
    int wr   = wid >> 2;   // 0..1  (M half)
    int wc   = wid & 3;    // 0..3  (N quarter)

    // ---- staging invariants (T2: inverse-swizzled global source, linear LDS dest) ----
    int sr   = lane >> 3;                    // row-within-8
    int k0   = ((lane & 7) ^ sr) << 3;       // swizzle-permuted k chunk (elements)
    int ldso = wid * 512 + lane * 8;         // linear dest offset (elements), round 0
    int grow = wid * 8 + sr;                 // row within 128-row half, round 0 (+64 rnd 1)

    const ushort* Abase = A + (size_t)(brow + grow) * K_DIM + k0;
    const ushort* Bbase = B + (size_t)(bcol + grow) * K_DIM + k0;

    // ---- fragment-read invariants (swizzled ds_read_b128) ----
    int lrow  = lane & 15;
    int klo   = lane >> 4;
    int sx    = (lrow & 7) << 4;
    int koff0 = (klo * 16) ^ sx;
    int koff1 = (64 + klo * 16) ^ sx;
    const char* ldsc = (const char*)lds;
    int aB = wr * 16384 + lrow * 128;
    int bB = 65536 + (wc >> 1) * 16384 + (wc & 1) * 8192 + lrow * 128;

    f32x4 acc[8][4];
#pragma unroll
    for (int i = 0; i < 8; ++i)
#pragma unroll
        for (int j = 0; j < 4; ++j)
            acc[i][j] = (f32x4){0.f, 0.f, 0.f, 0.f};

    bf16x8 aF[4][2], bL[2][2], bH[2][2];

    // prologue: stage tiles 0 and 1; wait tile 0 (8 newest = tile 1 stay in flight)
    STAGE_A(0, 0, 0); STAGE_A(0, 1, 0); STAGE_B(0, 0, 0); STAGE_B(0, 1, 0);
    STAGE_A(1, 0, 1); STAGE_A(1, 1, 1); STAGE_B(1, 0, 1); STAGE_B(1, 1, 1);
    asm volatile("s_waitcnt vmcnt(8)");
    __builtin_amdgcn_s_barrier();

    for (int kt2 = 0; kt2 < NT; kt2 += 2) {
        TILE(kt2, 0);
        TILE(kt2 + 1, 1);
    }

    // epilogue: C/D layout col=lane&15, row=(lane>>4)*4+reg
    int crow = brow + wr * 128 + klo * 4;
    int ccol = bcol + wc * 64 + lrow;
#pragma unroll
    for (int ni = 0; ni < 4; ++ni) {
        int col = ccol + (ni >> 1) * 32 + (ni & 1) * 16;
        float bv = bias[col];
#pragma unroll
        for (int mi = 0; mi < 8; ++mi) {
            int row = crow + (mi >> 2) * 64 + (mi & 3) * 16;
#pragma unroll
            for (int r = 0; r < 4; ++r)
                C[(size_t)(row + r) * N_DIM + col] = acc[mi][ni][r] + bv;
        }
    }
}

extern "C" void kernel_launch(void* const* d_in, const int* in_sizes, int n_in,
                              void* d_out, int out_size, void* d_ws, size_t ws_size,
                              hipStream_t stream) {
    const float* x = (const float*)d_in[0];   // (4096, 4096) f32
    const float* W = (const float*)d_in[1];   // (4096, 4096) f32
    const float* b = (const float*)d_in[2];   // (4096,) f32
    float* out = (float*)d_out;               // (4096, 4096) f32

    ushort* xq  = (ushort*)d_ws;                               // 32 MB: X as bf16 (M x K)
    ushort* WqT = (ushort*)d_ws + (size_t)M_DIM * K_DIM;       // 32 MB: sign(W) bf16, N x K

    cvt_x_kernel<<<2048, 256, 0, stream>>>(x, xq, M_DIM * K_DIM / 8);
    sign_wt_kernel<<<dim3(N_DIM / 32, K_DIM / 32), dim3(32, 8), 0, stream>>>(W, WqT);
    gemm_bin_kernel<<<dim3(256), dim3(512), 0, stream>>>(xq, WqT, b, out);
}